// Round 1
// baseline (177.268 us; speedup 1.0000x reference)
//
#include <hip/hip_runtime.h>
#include <hip/hip_bf16.h>
#include <stdint.h>

typedef __attribute__((ext_vector_type(8))) short bf16x8;
typedef __attribute__((ext_vector_type(4))) float f32x4;

#define AS1(p) ((const __attribute__((address_space(1))) uint32_t*)(p))
#define AS3(p) ((__attribute__((address_space(3))) uint32_t*)(p))

__device__ __forceinline__ ushort f2bf(float f) {
  uint32_t u = __float_as_uint(f);
  uint32_t r = (u + 0x7fffu + ((u >> 16) & 1u)) >> 16;
  return (ushort)r;
}

// ---------------- pack: fp32 -> bf16 (up to 4 tensors via blockIdx.y) ----------------
__global__ __launch_bounds__(256) void pack4(
    const float* __restrict__ s0, const float* __restrict__ s1,
    const float* __restrict__ s2, const float* __restrict__ s3,
    ushort* __restrict__ o0, ushort* __restrict__ o1,
    ushort* __restrict__ o2, ushort* __restrict__ o3, int n)
{
  const float* s; ushort* o;
  switch (blockIdx.y) {
    case 0: s = s0; o = o0; break;
    case 1: s = s1; o = o1; break;
    case 2: s = s2; o = o2; break;
    default: s = s3; o = o3; break;
  }
  int stride = gridDim.x * 1024;
  for (int i = (blockIdx.x * 256 + threadIdx.x) * 4; i < n; i += stride) {
    float4 v = *(const float4*)(s + i);
    ushort4 u;
    u.x = f2bf(v.x); u.y = f2bf(v.y); u.z = f2bf(v.z); u.w = f2bf(v.w);
    *(ushort4*)(o + i) = u;
  }
}

// ---------------- QKV projection GEMM: C[2048,512] = A[2048,4096] * W[512,4096]^T ----------------
// z = blockIdx.z selects (q,wq)->Qp, (k,wk)->Kp, (v,wv)->Vp. bf16 out.
__global__ __launch_bounds__(256) void gemm_qkv(
    const ushort* __restrict__ aq, const ushort* __restrict__ ak, const ushort* __restrict__ av,
    const ushort* __restrict__ wq, const ushort* __restrict__ wk, const ushort* __restrict__ wv,
    ushort* __restrict__ Qp, ushort* __restrict__ Kp, ushort* __restrict__ Vp)
{
  __shared__ __align__(16) ushort At[128 * 64];
  __shared__ __align__(16) ushort Bt[128 * 64];
  const ushort* A; const ushort* Bm; ushort* Dst;
  int z = blockIdx.z;
  if (z == 0)      { A = aq; Bm = wq; Dst = Qp; }
  else if (z == 1) { A = ak; Bm = wk; Dst = Kp; }
  else             { A = av; Bm = wv; Dst = Vp; }
  const int K = 4096;
  int rowBase = blockIdx.x * 128;   // 16 blocks -> 2048 rows
  int colBase = blockIdx.y * 128;   // 4 blocks  -> 512 cols
  int tid = threadIdx.x, l = tid & 63, w = tid >> 6;
  int wr = w >> 1, wc = w & 1, fr = l & 15, fq = l >> 4;
  f32x4 acc[4][4];
#pragma unroll
  for (int m = 0; m < 4; ++m)
#pragma unroll
    for (int n = 0; n < 4; ++n) acc[m][n] = (f32x4){0.f, 0.f, 0.f, 0.f};

  for (int kt = 0; kt < K; kt += 64) {
#pragma unroll
    for (int j = 0; j < 4; ++j) {
      int c = ((w * 4 + j) << 6) + l;   // 0..1023 chunk id (16B chunks)
      int row = c >> 3, cc = c & 7;
      __builtin_amdgcn_global_load_lds(AS1(A + (size_t)(rowBase + row) * K + kt + cc * 8),
                                       AS3((char*)At + (w * 4 + j) * 1024), 16, 0, 0);
      __builtin_amdgcn_global_load_lds(AS1(Bm + (size_t)(colBase + row) * K + kt + cc * 8),
                                       AS3((char*)Bt + (w * 4 + j) * 1024), 16, 0, 0);
    }
    __syncthreads();
#pragma unroll
    for (int kc = 0; kc < 2; ++kc) {
      bf16x8 af[4], bfv[4];
#pragma unroll
      for (int m = 0; m < 4; ++m)
        af[m] = *(const bf16x8*)&At[(wr * 64 + m * 16 + fr) * 64 + kc * 32 + fq * 8];
#pragma unroll
      for (int n = 0; n < 4; ++n)
        bfv[n] = *(const bf16x8*)&Bt[(wc * 64 + n * 16 + fr) * 64 + kc * 32 + fq * 8];
#pragma unroll
      for (int m = 0; m < 4; ++m)
#pragma unroll
        for (int n = 0; n < 4; ++n)
          acc[m][n] = __builtin_amdgcn_mfma_f32_16x16x32_bf16(af[m], bfv[n], acc[m][n], 0, 0, 0);
    }
    __syncthreads();
  }
#pragma unroll
  for (int m = 0; m < 4; ++m)
#pragma unroll
    for (int n = 0; n < 4; ++n)
#pragma unroll
      for (int r = 0; r < 4; ++r) {
        int row = rowBase + wr * 64 + m * 16 + fq * 4 + r;
        int col = colBase + wc * 64 + n * 16 + fr;
        Dst[(size_t)row * 512 + col] = f2bf(acc[m][n][r]);
      }
}

// ---------------- attention: per (b,h, row-half) block ----------------
__global__ __launch_bounds__(256) void attn(
    const ushort* __restrict__ Qp, const ushort* __restrict__ Kp, const ushort* __restrict__ Vp,
    float* __restrict__ Obuf, const float* __restrict__ temp)
{
  __shared__ __align__(16) ushort Qs[64 * 64];    // [crow][d]
  __shared__ __align__(16) ushort Ks[128 * 64];   // [e][d]
  __shared__ __align__(16) ushort Vt[64 * 128];   // [d][e] (transposed)
  __shared__ __align__(16) float  Sl[64 * 128];   // scores
  __shared__ __align__(16) ushort Pl[64 * 128];   // exp(S-max) bf16
  __shared__ float rsum[64];
  int bh = blockIdx.y, b = bh >> 3, h = bh & 7;
  int c0 = blockIdx.x * 64;
  int tid = threadIdx.x, l = tid & 63, w = tid >> 6;
  int wr = w >> 1, wc = w & 1, fr = l & 15, fq = l >> 4;
  float invT = 1.0f / temp[0];
  const size_t rowQ = (size_t)(b * 128 + c0);

  // stage Q (64 rows x 64 d)
#pragma unroll
  for (int j = 0; j < 2; ++j) {
    int c = ((w * 2 + j) << 6) + l, row = c >> 3, cc = c & 7;
    __builtin_amdgcn_global_load_lds(AS1(Qp + (rowQ + row) * 512 + h * 64 + cc * 8),
                                     AS3((char*)Qs + (w * 2 + j) * 1024), 16, 0, 0);
  }
  // stage K (128 rows x 64 d)
#pragma unroll
  for (int j = 0; j < 4; ++j) {
    int c = ((w * 4 + j) << 6) + l, row = c >> 3, cc = c & 7;
    __builtin_amdgcn_global_load_lds(AS1(Kp + (size_t)(b * 128 + row) * 512 + h * 64 + cc * 8),
                                     AS3((char*)Ks + (w * 4 + j) * 1024), 16, 0, 0);
  }
  // stage V transposed: Vt[d][e]
#pragma unroll
  for (int t = 0; t < 4; ++t) {
    int ch = tid + t * 256, e = ch >> 3, d0 = (ch & 7) * 8;
    bf16x8 vv = *(const bf16x8*)(Vp + (size_t)(b * 128 + e) * 512 + h * 64 + d0);
#pragma unroll
    for (int j = 0; j < 8; ++j) Vt[(d0 + j) * 128 + e] = (ushort)vv[j];
  }
  __syncthreads();

  // S = Q*K^T (64x128), wave quadrant: rows wr*32 (2 frags), cols wc*64 (4 frags)
  f32x4 sa[2][4];
#pragma unroll
  for (int m = 0; m < 2; ++m)
#pragma unroll
    for (int n = 0; n < 4; ++n) sa[m][n] = (f32x4){0.f, 0.f, 0.f, 0.f};
#pragma unroll
  for (int kc = 0; kc < 2; ++kc) {
    bf16x8 aQ[2], bK[4];
#pragma unroll
    for (int m = 0; m < 2; ++m)
      aQ[m] = *(const bf16x8*)&Qs[(wr * 32 + m * 16 + fr) * 64 + kc * 32 + fq * 8];
#pragma unroll
    for (int n = 0; n < 4; ++n)
      bK[n] = *(const bf16x8*)&Ks[(wc * 64 + n * 16 + fr) * 64 + kc * 32 + fq * 8];
#pragma unroll
    for (int m = 0; m < 2; ++m)
#pragma unroll
      for (int n = 0; n < 4; ++n)
        sa[m][n] = __builtin_amdgcn_mfma_f32_16x16x32_bf16(aQ[m], bK[n], sa[m][n], 0, 0, 0);
  }
#pragma unroll
  for (int m = 0; m < 2; ++m)
#pragma unroll
    for (int n = 0; n < 4; ++n)
#pragma unroll
      for (int r = 0; r < 4; ++r)
        Sl[(wr * 32 + m * 16 + fq * 4 + r) * 128 + wc * 64 + n * 16 + fr] = sa[m][n][r] * invT;
  __syncthreads();

  // softmax: 4 threads per row, 32 cols each
  {
    int row = tid >> 2, qq = tid & 3;
    const float* srow = Sl + row * 128 + qq * 32;
    float4 va[8];
#pragma unroll
    for (int i = 0; i < 8; ++i) va[i] = *(const float4*)(srow + i * 4);
    float mx = -1e30f;
#pragma unroll
    for (int i = 0; i < 8; ++i)
      mx = fmaxf(mx, fmaxf(fmaxf(va[i].x, va[i].y), fmaxf(va[i].z, va[i].w)));
    mx = fmaxf(mx, __shfl_xor(mx, 1));
    mx = fmaxf(mx, __shfl_xor(mx, 2));
    float ssum = 0.f;
    ushort* prow = Pl + row * 128 + qq * 32;
#pragma unroll
    for (int i = 0; i < 8; ++i) {
      float e0 = __expf(va[i].x - mx), e1 = __expf(va[i].y - mx);
      float e2 = __expf(va[i].z - mx), e3 = __expf(va[i].w - mx);
      ssum += (e0 + e1) + (e2 + e3);
      ushort4 u; u.x = f2bf(e0); u.y = f2bf(e1); u.z = f2bf(e2); u.w = f2bf(e3);
      *(ushort4*)(prow + i * 4) = u;
    }
    ssum += __shfl_xor(ssum, 1);
    ssum += __shfl_xor(ssum, 2);
    if (qq == 0) rsum[row] = ssum;
  }
  __syncthreads();

  // O = P*V (64x64), wave quadrant rows wr*32, cols wc*32; K=128 over e
  f32x4 oa[2][2];
#pragma unroll
  for (int m = 0; m < 2; ++m)
#pragma unroll
    for (int n = 0; n < 2; ++n) oa[m][n] = (f32x4){0.f, 0.f, 0.f, 0.f};
#pragma unroll
  for (int kc = 0; kc < 4; ++kc) {
    bf16x8 aP[2], bV[2];
#pragma unroll
    for (int m = 0; m < 2; ++m)
      aP[m] = *(const bf16x8*)&Pl[(wr * 32 + m * 16 + fr) * 128 + kc * 32 + fq * 8];
#pragma unroll
    for (int n = 0; n < 2; ++n)
      bV[n] = *(const bf16x8*)&Vt[(wc * 32 + n * 16 + fr) * 128 + kc * 32 + fq * 8];
#pragma unroll
    for (int m = 0; m < 2; ++m)
#pragma unroll
      for (int n = 0; n < 2; ++n)
        oa[m][n] = __builtin_amdgcn_mfma_f32_16x16x32_bf16(aP[m], bV[n], oa[m][n], 0, 0, 0);
  }
#pragma unroll
  for (int m = 0; m < 2; ++m)
#pragma unroll
    for (int n = 0; n < 2; ++n)
#pragma unroll
      for (int r = 0; r < 4; ++r) {
        int row = wr * 32 + m * 16 + fq * 4 + r, col = wc * 32 + n * 16 + fr;
        Obuf[(rowQ + row) * 512 + h * 64 + col] = oa[m][n][r] / rsum[row];
      }
}

// ---------------- swish + LayerNorm over D=512, out bf16 ----------------
__global__ __launch_bounds__(256) void swish_ln(
    const float* __restrict__ O, ushort* __restrict__ X,
    const float* __restrict__ gamma, const float* __restrict__ beta)
{
  int row = blockIdx.x, tid = threadIdx.x;
  const float* x = O + (size_t)row * 512;
  float2 v = *(const float2*)(x + tid * 2);
  float y0 = v.x / (1.f + __expf(-v.x));
  float y1 = v.y / (1.f + __expf(-v.y));
  float s = y0 + y1, sq = y0 * y0 + y1 * y1;
#pragma unroll
  for (int o = 1; o < 64; o <<= 1) { s += __shfl_xor(s, o); sq += __shfl_xor(sq, o); }
  __shared__ float red[8];
  int wv = tid >> 6;
  if ((tid & 63) == 0) { red[wv] = s; red[wv + 4] = sq; }
  __syncthreads();
  s = red[0] + red[1] + red[2] + red[3];
  sq = red[4] + red[5] + red[6] + red[7];
  float mean = s * (1.f / 512.f);
  float var = (sq - s * mean) * (1.f / 511.f);   // unbiased (ddof=1)
  float inv = 1.f / (sqrtf(var) + 1e-6f);
  int c = tid * 2;
  float r0 = gamma[c] * (y0 - mean) * inv + beta[c];
  float r1 = gamma[c + 1] * (y1 - mean) * inv + beta[c + 1];
  ushort2 u; u.x = f2bf(r0); u.y = f2bf(r1);
  *(ushort2*)(X + (size_t)row * 512 + c) = u;
}

// ---------------- fc GEMM + residual + BN partial sums ----------------
__global__ __launch_bounds__(256) void gemm_fc(
    const ushort* __restrict__ A, const ushort* __restrict__ Bm,
    const float* __restrict__ resid, float* __restrict__ out,
    float* __restrict__ bn_sum, float* __restrict__ bn_sq)
{
  __shared__ __align__(16) ushort At[128 * 64];
  __shared__ __align__(16) ushort Bt[128 * 64];
  __shared__ float csum[128], csq[128];
  const int K = 512;
  int rowBase = blockIdx.x * 128;   // 16
  int colBase = blockIdx.y * 128;   // 32
  int tid = threadIdx.x, l = tid & 63, w = tid >> 6;
  int wr = w >> 1, wc = w & 1, fr = l & 15, fq = l >> 4;
  if (tid < 128) { csum[tid] = 0.f; csq[tid] = 0.f; }
  f32x4 acc[4][4];
#pragma unroll
  for (int m = 0; m < 4; ++m)
#pragma unroll
    for (int n = 0; n < 4; ++n) acc[m][n] = (f32x4){0.f, 0.f, 0.f, 0.f};

  for (int kt = 0; kt < K; kt += 64) {
#pragma unroll
    for (int j = 0; j < 4; ++j) {
      int c = ((w * 4 + j) << 6) + l;
      int row = c >> 3, cc = c & 7;
      __builtin_amdgcn_global_load_lds(AS1(A + (size_t)(rowBase + row) * K + kt + cc * 8),
                                       AS3((char*)At + (w * 4 + j) * 1024), 16, 0, 0);
      __builtin_amdgcn_global_load_lds(AS1(Bm + (size_t)(colBase + row) * K + kt + cc * 8),
                                       AS3((char*)Bt + (w * 4 + j) * 1024), 16, 0, 0);
    }
    __syncthreads();
#pragma unroll
    for (int kc = 0; kc < 2; ++kc) {
      bf16x8 af[4], bfv[4];
#pragma unroll
      for (int m = 0; m < 4; ++m)
        af[m] = *(const bf16x8*)&At[(wr * 64 + m * 16 + fr) * 64 + kc * 32 + fq * 8];
#pragma unroll
      for (int n = 0; n < 4; ++n)
        bfv[n] = *(const bf16x8*)&Bt[(wc * 64 + n * 16 + fr) * 64 + kc * 32 + fq * 8];
#pragma unroll
      for (int m = 0; m < 4; ++m)
#pragma unroll
        for (int n = 0; n < 4; ++n)
          acc[m][n] = __builtin_amdgcn_mfma_f32_16x16x32_bf16(af[m], bfv[n], acc[m][n], 0, 0, 0);
    }
    __syncthreads();
  }
  // epilogue: out = acc + residual; per-channel partial sums for BN
#pragma unroll
  for (int m = 0; m < 4; ++m)
#pragma unroll
    for (int r = 0; r < 4; ++r) {
      float ps = 0.f, pq = 0.f;
#pragma unroll
      for (int n = 0; n < 4; ++n) {
        int row = rowBase + wr * 64 + m * 16 + fq * 4 + r;
        int col = colBase + wc * 64 + n * 16 + fr;
        size_t idx = (size_t)row * 4096 + col;
        float val = acc[m][n][r] + resid[idx];
        out[idx] = val;
        ps += val; pq += val * val;
      }
#pragma unroll
      for (int o = 1; o < 16; o <<= 1) { ps += __shfl_xor(ps, o); pq += __shfl_xor(pq, o); }
      if (fr == 0) {
        int ch = wr * 64 + m * 16 + fq * 4 + r;   // rowBase % 128 == 0
        atomicAdd(&csum[ch], ps);
        atomicAdd(&csq[ch], pq);
      }
    }
  __syncthreads();
  if (tid < 128) {
    atomicAdd(&bn_sum[tid], csum[tid]);
    atomicAdd(&bn_sq[tid], csq[tid]);
  }
}

// ---------------- BatchNorm finalize (in place on d_out) ----------------
__global__ __launch_bounds__(256) void bn_norm(
    float* __restrict__ out, const float* __restrict__ bn_sum, const float* __restrict__ bn_sq,
    const float* __restrict__ gamma, const float* __restrict__ beta)
{
  const float inv_n = 1.f / 65536.f;
  int stride = gridDim.x * blockDim.x;
  for (int v = blockIdx.x * blockDim.x + threadIdx.x; v < 2097152; v += stride) {
    int elem = v * 4;
    int ch = (elem >> 12) & 127;
    float mean = bn_sum[ch] * inv_n;
    float var = bn_sq[ch] * inv_n - mean * mean;
    float g = gamma[ch] * rsqrtf(var + 1e-5f);
    float bta = beta[ch];
    float4 x = *(float4*)(out + elem);
    x.x = (x.x - mean) * g + bta;
    x.y = (x.y - mean) * g + bta;
    x.z = (x.z - mean) * g + bta;
    x.w = (x.w - mean) * g + bta;
    *(float4*)(out + elem) = x;
  }
}

extern "C" void kernel_launch(void* const* d_in, const int* in_sizes, int n_in,
                              void* d_out, int out_size, void* d_ws, size_t ws_size,
                              hipStream_t stream)
{
  const float* v_in = (const float*)d_in[0];
  const float* k_in = (const float*)d_in[1];
  const float* q_in = (const float*)d_in[2];
  const float* w_qs = (const float*)d_in[3];
  const float* w_ks = (const float*)d_in[4];
  const float* w_vs = (const float*)d_in[5];
  const float* w_fc = (const float*)d_in[6];
  const float* ln_g = (const float*)d_in[7];
  const float* ln_b = (const float*)d_in[8];
  const float* temp = (const float*)d_in[9];
  const float* bn_g = (const float*)d_in[10];
  const float* bn_b = (const float*)d_in[11];
  float* out = (float*)d_out;

  char* ws = (char*)d_ws;
  size_t off = 0;
  auto alloc = [&](size_t bytes) { char* p = ws + off; off += bytes; return p; };
  ushort* bq  = (ushort*)alloc(2048ull * 4096 * 2);
  ushort* bk  = (ushort*)alloc(2048ull * 4096 * 2);
  ushort* bv  = (ushort*)alloc(2048ull * 4096 * 2);
  ushort* wq  = (ushort*)alloc(512ull * 4096 * 2);
  ushort* wk  = (ushort*)alloc(512ull * 4096 * 2);
  ushort* wv  = (ushort*)alloc(512ull * 4096 * 2);
  ushort* wfc = (ushort*)alloc(512ull * 4096 * 2);
  ushort* Qp  = (ushort*)alloc(2048ull * 512 * 2);
  ushort* Kp  = (ushort*)alloc(2048ull * 512 * 2);
  ushort* Vp  = (ushort*)alloc(2048ull * 512 * 2);
  float*  Obuf= (float*)alloc(2048ull * 512 * 4);
  ushort* X16 = (ushort*)alloc(2048ull * 512 * 2);
  float*  bns = (float*)alloc(128 * 4);
  float*  bnq = (float*)alloc(128 * 4);

  hipMemsetAsync(bns, 0, 256 * 4, stream);   // zero bns+bnq (adjacent)

  pack4<<<dim3(1024, 3), 256, 0, stream>>>(q_in, k_in, v_in, nullptr, bq, bk, bv, nullptr,
                                           2048 * 4096);
  pack4<<<dim3(512, 4), 256, 0, stream>>>(w_qs, w_ks, w_vs, w_fc, wq, wk, wv, wfc,
                                          512 * 4096);
  gemm_qkv<<<dim3(16, 4, 3), 256, 0, stream>>>(bq, bk, bv, wq, wk, wv, Qp, Kp, Vp);
  attn<<<dim3(2, 128), 256, 0, stream>>>(Qp, Kp, Vp, Obuf, temp);
  swish_ln<<<2048, 256, 0, stream>>>(Obuf, X16, ln_g, ln_b);
  gemm_fc<<<dim3(16, 32), 256, 0, stream>>>(X16, wfc, v_in, out, bns, bnq);
  bn_norm<<<2048, 256, 0, stream>>>(out, bns, bnq, bn_g, bn_b);
}

// Round 2
// 159.609 us; speedup vs baseline: 1.1106x; 1.1106x over previous
//
#include <hip/hip_runtime.h>
#include <hip/hip_bf16.h>
#include <stdint.h>

typedef __attribute__((ext_vector_type(8))) short bf16x8;
typedef __attribute__((ext_vector_type(4))) float f32x4;

#define AS1(p) ((const __attribute__((address_space(1))) uint32_t*)(p))
#define AS3(p) ((__attribute__((address_space(3))) uint32_t*)(p))

__device__ __forceinline__ ushort f2bf(float f) {
  uint32_t u = __float_as_uint(f);
  uint32_t r = (u + 0x7fffu + ((u >> 16) & 1u)) >> 16;
  return (ushort)r;
}

// ---------------- pack: fp32 -> bf16 (up to 4 tensors via blockIdx.y) ----------------
__global__ __launch_bounds__(256) void pack4(
    const float* __restrict__ s0, const float* __restrict__ s1,
    const float* __restrict__ s2, const float* __restrict__ s3,
    ushort* __restrict__ o0, ushort* __restrict__ o1,
    ushort* __restrict__ o2, ushort* __restrict__ o3, int n)
{
  const float* s; ushort* o;
  switch (blockIdx.y) {
    case 0: s = s0; o = o0; break;
    case 1: s = s1; o = o1; break;
    case 2: s = s2; o = o2; break;
    default: s = s3; o = o3; break;
  }
  int stride = gridDim.x * 1024;
  for (int i = (blockIdx.x * 256 + threadIdx.x) * 4; i < n; i += stride) {
    float4 v = *(const float4*)(s + i);
    ushort4 u;
    u.x = f2bf(v.x); u.y = f2bf(v.y); u.z = f2bf(v.z); u.w = f2bf(v.w);
    *(ushort4*)(o + i) = u;
  }
}

// ---------------- QKV projection GEMM, split-K ----------------
// C[2048,512] = A[2048,4096] * W[512,4096]^T  for 3 (A,W) pairs.
// blockIdx.z -> (gemm g, split s); each block computes a 128x128 tile over a
// K-chunk of 4096>>lgs and writes an fp32 partial plane.
__global__ __launch_bounds__(256) void gemm_qkv(
    const ushort* __restrict__ aq, const ushort* __restrict__ ak, const ushort* __restrict__ av,
    const ushort* __restrict__ wq, const ushort* __restrict__ wk, const ushort* __restrict__ wv,
    float* __restrict__ part, int lgs)
{
  __shared__ __align__(16) ushort At[128 * 64];
  __shared__ __align__(16) ushort Bt[128 * 64];
  int z = blockIdx.z;
  int g = z >> lgs, s = z & ((1 << lgs) - 1);
  const ushort* A; const ushort* Bm;
  if (g == 0)      { A = aq; Bm = wq; }
  else if (g == 1) { A = ak; Bm = wk; }
  else             { A = av; Bm = wv; }
  float* Pd = part + ((size_t)z) * 1048576;   // z == (g<<lgs)+s, plane 2048*512
  const int K = 4096;
  const int kchunk = K >> lgs;
  const int k0 = s * kchunk;
  int rowBase = blockIdx.x * 128;   // 16 blocks -> 2048 rows
  int colBase = blockIdx.y * 128;   // 4 blocks  -> 512 cols
  int tid = threadIdx.x, l = tid & 63, w = tid >> 6;
  int wr = w >> 1, wc = w & 1, fr = l & 15, fq = l >> 4;
  f32x4 acc[4][4];
#pragma unroll
  for (int m = 0; m < 4; ++m)
#pragma unroll
    for (int n = 0; n < 4; ++n) acc[m][n] = (f32x4){0.f, 0.f, 0.f, 0.f};

  for (int kt = k0; kt < k0 + kchunk; kt += 64) {
#pragma unroll
    for (int j = 0; j < 4; ++j) {
      int c = ((w * 4 + j) << 6) + l;   // 0..1023 chunk id (16B chunks)
      int row = c >> 3, cc = c & 7;
      __builtin_amdgcn_global_load_lds(AS1(A + (size_t)(rowBase + row) * K + kt + cc * 8),
                                       AS3((char*)At + (w * 4 + j) * 1024), 16, 0, 0);
      __builtin_amdgcn_global_load_lds(AS1(Bm + (size_t)(colBase + row) * K + kt + cc * 8),
                                       AS3((char*)Bt + (w * 4 + j) * 1024), 16, 0, 0);
    }
    __syncthreads();
#pragma unroll
    for (int kc = 0; kc < 2; ++kc) {
      bf16x8 af[4], bfv[4];
#pragma unroll
      for (int m = 0; m < 4; ++m)
        af[m] = *(const bf16x8*)&At[(wr * 64 + m * 16 + fr) * 64 + kc * 32 + fq * 8];
#pragma unroll
      for (int n = 0; n < 4; ++n)
        bfv[n] = *(const bf16x8*)&Bt[(wc * 64 + n * 16 + fr) * 64 + kc * 32 + fq * 8];
#pragma unroll
      for (int m = 0; m < 4; ++m)
#pragma unroll
        for (int n = 0; n < 4; ++n)
          acc[m][n] = __builtin_amdgcn_mfma_f32_16x16x32_bf16(af[m], bfv[n], acc[m][n], 0, 0, 0);
    }
    __syncthreads();
  }
#pragma unroll
  for (int m = 0; m < 4; ++m)
#pragma unroll
    for (int n = 0; n < 4; ++n)
#pragma unroll
      for (int r = 0; r < 4; ++r) {
        int row = rowBase + wr * 64 + m * 16 + fq * 4 + r;
        int col = colBase + wc * 64 + n * 16 + fr;
        Pd[(size_t)row * 512 + col] = acc[m][n][r];
      }
}

// ---------------- reduce split-K partials -> bf16 Q/K/V ----------------
__global__ __launch_bounds__(256) void reduce_qkv(
    const float* __restrict__ part, ushort* __restrict__ Qp, ushort* __restrict__ Kp,
    ushort* __restrict__ Vp, int lgs)
{
  int g = blockIdx.y;
  ushort* dst = g == 0 ? Qp : (g == 1 ? Kp : Vp);
  const float* p = part + (((size_t)g) << lgs) * 1048576;
  int i = (blockIdx.x * 256 + threadIdx.x) * 4;
  float4 acc = *(const float4*)(p + i);
  int splits = 1 << lgs;
  for (int s = 1; s < splits; ++s) {
    float4 b = *(const float4*)(p + (size_t)s * 1048576 + i);
    acc.x += b.x; acc.y += b.y; acc.z += b.z; acc.w += b.w;
  }
  ushort4 u;
  u.x = f2bf(acc.x); u.y = f2bf(acc.y); u.z = f2bf(acc.z); u.w = f2bf(acc.w);
  *(ushort4*)(dst + i) = u;
}

// ---------------- attention: per (b,h, row-half) block ----------------
__global__ __launch_bounds__(256) void attn(
    const ushort* __restrict__ Qp, const ushort* __restrict__ Kp, const ushort* __restrict__ Vp,
    float* __restrict__ Obuf, const float* __restrict__ temp)
{
  __shared__ __align__(16) ushort Qs[64 * 64];    // [crow][d]
  __shared__ __align__(16) ushort Ks[128 * 64];   // [e][d]
  __shared__ __align__(16) ushort Vt[64 * 128];   // [d][e] (transposed)
  __shared__ __align__(16) float  Sl[64 * 128];   // scores
  __shared__ __align__(16) ushort Pl[64 * 128];   // exp(S-max) bf16
  __shared__ float rsum[64];
  int bh = blockIdx.y, b = bh >> 3, h = bh & 7;
  int c0 = blockIdx.x * 64;
  int tid = threadIdx.x, l = tid & 63, w = tid >> 6;
  int wr = w >> 1, wc = w & 1, fr = l & 15, fq = l >> 4;
  float invT = 1.0f / temp[0];
  const size_t rowQ = (size_t)(b * 128 + c0);

  // stage Q (64 rows x 64 d)
#pragma unroll
  for (int j = 0; j < 2; ++j) {
    int c = ((w * 2 + j) << 6) + l, row = c >> 3, cc = c & 7;
    __builtin_amdgcn_global_load_lds(AS1(Qp + (rowQ + row) * 512 + h * 64 + cc * 8),
                                     AS3((char*)Qs + (w * 2 + j) * 1024), 16, 0, 0);
  }
  // stage K (128 rows x 64 d)
#pragma unroll
  for (int j = 0; j < 4; ++j) {
    int c = ((w * 4 + j) << 6) + l, row = c >> 3, cc = c & 7;
    __builtin_amdgcn_global_load_lds(AS1(Kp + (size_t)(b * 128 + row) * 512 + h * 64 + cc * 8),
                                     AS3((char*)Ks + (w * 4 + j) * 1024), 16, 0, 0);
  }
  // stage V transposed: Vt[d][e]
#pragma unroll
  for (int t = 0; t < 4; ++t) {
    int ch = tid + t * 256, e = ch >> 3, d0 = (ch & 7) * 8;
    bf16x8 vv = *(const bf16x8*)(Vp + (size_t)(b * 128 + e) * 512 + h * 64 + d0);
#pragma unroll
    for (int j = 0; j < 8; ++j) Vt[(d0 + j) * 128 + e] = (ushort)vv[j];
  }
  __syncthreads();

  // S = Q*K^T (64x128), wave quadrant: rows wr*32 (2 frags), cols wc*64 (4 frags)
  f32x4 sa[2][4];
#pragma unroll
  for (int m = 0; m < 2; ++m)
#pragma unroll
    for (int n = 0; n < 4; ++n) sa[m][n] = (f32x4){0.f, 0.f, 0.f, 0.f};
#pragma unroll
  for (int kc = 0; kc < 2; ++kc) {
    bf16x8 aQ[2], bK[4];
#pragma unroll
    for (int m = 0; m < 2; ++m)
      aQ[m] = *(const bf16x8*)&Qs[(wr * 32 + m * 16 + fr) * 64 + kc * 32 + fq * 8];
#pragma unroll
    for (int n = 0; n < 4; ++n)
      bK[n] = *(const bf16x8*)&Ks[(wc * 64 + n * 16 + fr) * 64 + kc * 32 + fq * 8];
#pragma unroll
    for (int m = 0; m < 2; ++m)
#pragma unroll
      for (int n = 0; n < 4; ++n)
        sa[m][n] = __builtin_amdgcn_mfma_f32_16x16x32_bf16(aQ[m], bK[n], sa[m][n], 0, 0, 0);
  }
#pragma unroll
  for (int m = 0; m < 2; ++m)
#pragma unroll
    for (int n = 0; n < 4; ++n)
#pragma unroll
      for (int r = 0; r < 4; ++r)
        Sl[(wr * 32 + m * 16 + fq * 4 + r) * 128 + wc * 64 + n * 16 + fr] = sa[m][n][r] * invT;
  __syncthreads();

  // softmax: 4 threads per row, 32 cols each
  {
    int row = tid >> 2, qq = tid & 3;
    const float* srow = Sl + row * 128 + qq * 32;
    float4 va[8];
#pragma unroll
    for (int i = 0; i < 8; ++i) va[i] = *(const float4*)(srow + i * 4);
    float mx = -1e30f;
#pragma unroll
    for (int i = 0; i < 8; ++i)
      mx = fmaxf(mx, fmaxf(fmaxf(va[i].x, va[i].y), fmaxf(va[i].z, va[i].w)));
    mx = fmaxf(mx, __shfl_xor(mx, 1));
    mx = fmaxf(mx, __shfl_xor(mx, 2));
    float ssum = 0.f;
    ushort* prow = Pl + row * 128 + qq * 32;
#pragma unroll
    for (int i = 0; i < 8; ++i) {
      float e0 = __expf(va[i].x - mx), e1 = __expf(va[i].y - mx);
      float e2 = __expf(va[i].z - mx), e3 = __expf(va[i].w - mx);
      ssum += (e0 + e1) + (e2 + e3);
      ushort4 u; u.x = f2bf(e0); u.y = f2bf(e1); u.z = f2bf(e2); u.w = f2bf(e3);
      *(ushort4*)(prow + i * 4) = u;
    }
    ssum += __shfl_xor(ssum, 1);
    ssum += __shfl_xor(ssum, 2);
    if (qq == 0) rsum[row] = ssum;
  }
  __syncthreads();

  // O = P*V (64x64), wave quadrant rows wr*32, cols wc*32; K=128 over e
  f32x4 oa[2][2];
#pragma unroll
  for (int m = 0; m < 2; ++m)
#pragma unroll
    for (int n = 0; n < 2; ++n) oa[m][n] = (f32x4){0.f, 0.f, 0.f, 0.f};
#pragma unroll
  for (int kc = 0; kc < 4; ++kc) {
    bf16x8 aP[2], bV[2];
#pragma unroll
    for (int m = 0; m < 2; ++m)
      aP[m] = *(const bf16x8*)&Pl[(wr * 32 + m * 16 + fr) * 128 + kc * 32 + fq * 8];
#pragma unroll
    for (int n = 0; n < 2; ++n)
      bV[n] = *(const bf16x8*)&Vt[(wc * 32 + n * 16 + fr) * 128 + kc * 32 + fq * 8];
#pragma unroll
    for (int m = 0; m < 2; ++m)
#pragma unroll
      for (int n = 0; n < 2; ++n)
        oa[m][n] = __builtin_amdgcn_mfma_f32_16x16x32_bf16(aP[m], bV[n], oa[m][n], 0, 0, 0);
  }
#pragma unroll
  for (int m = 0; m < 2; ++m)
#pragma unroll
    for (int n = 0; n < 2; ++n)
#pragma unroll
      for (int r = 0; r < 4; ++r) {
        int row = wr * 32 + m * 16 + fq * 4 + r, col = wc * 32 + n * 16 + fr;
        Obuf[(rowQ + row) * 512 + h * 64 + col] = oa[m][n][r] / rsum[row];
      }
}

// ---------------- swish + LayerNorm over D=512, out bf16 ----------------
__global__ __launch_bounds__(256) void swish_ln(
    const float* __restrict__ O, ushort* __restrict__ X,
    const float* __restrict__ gamma, const float* __restrict__ beta)
{
  int row = blockIdx.x, tid = threadIdx.x;
  const float* x = O + (size_t)row * 512;
  float2 v = *(const float2*)(x + tid * 2);
  float y0 = v.x / (1.f + __expf(-v.x));
  float y1 = v.y / (1.f + __expf(-v.y));
  float s = y0 + y1, sq = y0 * y0 + y1 * y1;
#pragma unroll
  for (int o = 1; o < 64; o <<= 1) { s += __shfl_xor(s, o); sq += __shfl_xor(sq, o); }
  __shared__ float red[8];
  int wv = tid >> 6;
  if ((tid & 63) == 0) { red[wv] = s; red[wv + 4] = sq; }
  __syncthreads();
  s = red[0] + red[1] + red[2] + red[3];
  sq = red[4] + red[5] + red[6] + red[7];
  float mean = s * (1.f / 512.f);
  float var = (sq - s * mean) * (1.f / 511.f);   // unbiased (ddof=1)
  float inv = 1.f / (sqrtf(var) + 1e-6f);
  int c = tid * 2;
  float r0 = gamma[c] * (y0 - mean) * inv + beta[c];
  float r1 = gamma[c + 1] * (y1 - mean) * inv + beta[c + 1];
  ushort2 u; u.x = f2bf(r0); u.y = f2bf(r1);
  *(ushort2*)(X + (size_t)row * 512 + c) = u;
}

// ---------------- fc GEMM + residual + BN partial sums ----------------
__global__ __launch_bounds__(256) void gemm_fc(
    const ushort* __restrict__ A, const ushort* __restrict__ Bm,
    const float* __restrict__ resid, float* __restrict__ out,
    float* __restrict__ bn_sum, float* __restrict__ bn_sq)
{
  __shared__ __align__(16) ushort At[128 * 64];
  __shared__ __align__(16) ushort Bt[128 * 64];
  __shared__ float csum[128], csq[128];
  const int K = 512;
  int rowBase = blockIdx.x * 128;   // 16
  int colBase = blockIdx.y * 128;   // 32
  int tid = threadIdx.x, l = tid & 63, w = tid >> 6;
  int wr = w >> 1, wc = w & 1, fr = l & 15, fq = l >> 4;
  if (tid < 128) { csum[tid] = 0.f; csq[tid] = 0.f; }
  f32x4 acc[4][4];
#pragma unroll
  for (int m = 0; m < 4; ++m)
#pragma unroll
    for (int n = 0; n < 4; ++n) acc[m][n] = (f32x4){0.f, 0.f, 0.f, 0.f};

  for (int kt = 0; kt < K; kt += 64) {
#pragma unroll
    for (int j = 0; j < 4; ++j) {
      int c = ((w * 4 + j) << 6) + l;
      int row = c >> 3, cc = c & 7;
      __builtin_amdgcn_global_load_lds(AS1(A + (size_t)(rowBase + row) * K + kt + cc * 8),
                                       AS3((char*)At + (w * 4 + j) * 1024), 16, 0, 0);
      __builtin_amdgcn_global_load_lds(AS1(Bm + (size_t)(colBase + row) * K + kt + cc * 8),
                                       AS3((char*)Bt + (w * 4 + j) * 1024), 16, 0, 0);
    }
    __syncthreads();
#pragma unroll
    for (int kc = 0; kc < 2; ++kc) {
      bf16x8 af[4], bfv[4];
#pragma unroll
      for (int m = 0; m < 4; ++m)
        af[m] = *(const bf16x8*)&At[(wr * 64 + m * 16 + fr) * 64 + kc * 32 + fq * 8];
#pragma unroll
      for (int n = 0; n < 4; ++n)
        bfv[n] = *(const bf16x8*)&Bt[(wc * 64 + n * 16 + fr) * 64 + kc * 32 + fq * 8];
#pragma unroll
      for (int m = 0; m < 4; ++m)
#pragma unroll
        for (int n = 0; n < 4; ++n)
          acc[m][n] = __builtin_amdgcn_mfma_f32_16x16x32_bf16(af[m], bfv[n], acc[m][n], 0, 0, 0);
    }
    __syncthreads();
  }
  // epilogue: out = acc + residual; per-channel partial sums for BN
#pragma unroll
  for (int m = 0; m < 4; ++m)
#pragma unroll
    for (int r = 0; r < 4; ++r) {
      float ps = 0.f, pq = 0.f;
#pragma unroll
      for (int n = 0; n < 4; ++n) {
        int row = rowBase + wr * 64 + m * 16 + fq * 4 + r;
        int col = colBase + wc * 64 + n * 16 + fr;
        size_t idx = (size_t)row * 4096 + col;
        float val = acc[m][n][r] + resid[idx];
        out[idx] = val;
        ps += val; pq += val * val;
      }
#pragma unroll
      for (int o = 1; o < 16; o <<= 1) { ps += __shfl_xor(ps, o); pq += __shfl_xor(pq, o); }
      if (fr == 0) {
        int ch = wr * 64 + m * 16 + fq * 4 + r;   // rowBase % 128 == 0
        atomicAdd(&csum[ch], ps);
        atomicAdd(&csq[ch], pq);
      }
    }
  __syncthreads();
  if (tid < 128) {
    atomicAdd(&bn_sum[tid], csum[tid]);
    atomicAdd(&bn_sq[tid], csq[tid]);
  }
}

// ---------------- BatchNorm finalize (in place on d_out) ----------------
__global__ __launch_bounds__(256) void bn_norm(
    float* __restrict__ out, const float* __restrict__ bn_sum, const float* __restrict__ bn_sq,
    const float* __restrict__ gamma, const float* __restrict__ beta)
{
  const float inv_n = 1.f / 65536.f;
  int stride = gridDim.x * blockDim.x;
  for (int v = blockIdx.x * blockDim.x + threadIdx.x; v < 2097152; v += stride) {
    int elem = v * 4;
    int ch = (elem >> 12) & 127;
    float mean = bn_sum[ch] * inv_n;
    float var = bn_sq[ch] * inv_n - mean * mean;
    float g = gamma[ch] * rsqrtf(var + 1e-5f);
    float bta = beta[ch];
    float4 x = *(float4*)(out + elem);
    x.x = (x.x - mean) * g + bta;
    x.y = (x.y - mean) * g + bta;
    x.z = (x.z - mean) * g + bta;
    x.w = (x.w - mean) * g + bta;
    *(float4*)(out + elem) = x;
  }
}

extern "C" void kernel_launch(void* const* d_in, const int* in_sizes, int n_in,
                              void* d_out, int out_size, void* d_ws, size_t ws_size,
                              hipStream_t stream)
{
  const float* v_in = (const float*)d_in[0];
  const float* k_in = (const float*)d_in[1];
  const float* q_in = (const float*)d_in[2];
  const float* w_qs = (const float*)d_in[3];
  const float* w_ks = (const float*)d_in[4];
  const float* w_vs = (const float*)d_in[5];
  const float* w_fc = (const float*)d_in[6];
  const float* ln_g = (const float*)d_in[7];
  const float* ln_b = (const float*)d_in[8];
  const float* temp = (const float*)d_in[9];
  const float* bn_g = (const float*)d_in[10];
  const float* bn_b = (const float*)d_in[11];
  float* out = (float*)d_out;

  char* ws = (char*)d_ws;
  size_t off = 0;
  auto alloc = [&](size_t bytes) { char* p = ws + off; off += bytes; return p; };
  ushort* bq  = (ushort*)alloc(2048ull * 4096 * 2);
  ushort* bk  = (ushort*)alloc(2048ull * 4096 * 2);
  ushort* bv  = (ushort*)alloc(2048ull * 4096 * 2);
  ushort* wq  = (ushort*)alloc(512ull * 4096 * 2);
  ushort* wk  = (ushort*)alloc(512ull * 4096 * 2);
  ushort* wv  = (ushort*)alloc(512ull * 4096 * 2);
  ushort* wfc = (ushort*)alloc(512ull * 4096 * 2);
  ushort* Qp  = (ushort*)alloc(2048ull * 512 * 2);
  ushort* Kp  = (ushort*)alloc(2048ull * 512 * 2);
  ushort* Vp  = (ushort*)alloc(2048ull * 512 * 2);
  float*  Obuf= (float*)alloc(2048ull * 512 * 4);
  ushort* X16 = (ushort*)alloc(2048ull * 512 * 2);
  float*  bns = (float*)alloc(128 * 4);
  float*  bnq = (float*)alloc(128 * 4);

  // split-K partial planes: 3*(1<<lgs) planes of 2048*512 fp32
  int lgs = 2;                       // 4-way split-K -> 768 blocks (3 blocks/CU)
  if (off + (3ull << lgs) * 1048576 * 4 > ws_size) lgs = 1;
  if (off + (3ull << lgs) * 1048576 * 4 > ws_size) lgs = 0;
  float* part = (float*)alloc((3ull << lgs) * 1048576 * 4);

  hipMemsetAsync(bns, 0, 256 * 4, stream);   // zero bns+bnq (adjacent)

  pack4<<<dim3(1024, 3), 256, 0, stream>>>(q_in, k_in, v_in, nullptr, bq, bk, bv, nullptr,
                                           2048 * 4096);
  pack4<<<dim3(512, 4), 256, 0, stream>>>(w_qs, w_ks, w_vs, w_fc, wq, wk, wv, wfc,
                                          512 * 4096);
  gemm_qkv<<<dim3(16, 4, 3 << lgs), 256, 0, stream>>>(bq, bk, bv, wq, wk, wv, part, lgs);
  reduce_qkv<<<dim3(1024, 3), 256, 0, stream>>>(part, Qp, Kp, Vp, lgs);
  attn<<<dim3(2, 128), 256, 0, stream>>>(Qp, Kp, Vp, Obuf, temp);
  swish_ln<<<2048, 256, 0, stream>>>(Obuf, X16, ln_g, ln_b);
  gemm_fc<<<dim3(16, 32), 256, 0, stream>>>(X16, wfc, v_in, out, bns, bnq);
  bn_norm<<<2048, 256, 0, stream>>>(out, bns, bnq, bn_g, bn_b);
}

// Round 3
// 150.607 us; speedup vs baseline: 1.1770x; 1.0598x over previous
//
#include <hip/hip_runtime.h>
#include <hip/hip_bf16.h>
#include <stdint.h>

typedef __attribute__((ext_vector_type(8))) short bf16x8;
typedef __attribute__((ext_vector_type(4))) float f32x4;

#define AS1(p) ((const __attribute__((address_space(1))) uint32_t*)(p))
#define AS3(p) ((__attribute__((address_space(3))) uint32_t*)(p))

__device__ __forceinline__ ushort f2bf(float f) {
  uint32_t u = __float_as_uint(f);
  uint32_t r = (u + 0x7fffu + ((u >> 16) & 1u)) >> 16;
  return (ushort)r;
}

// ---------------- pack: fp32 -> bf16 (weights only now) ----------------
__global__ __launch_bounds__(256) void pack4(
    const float* __restrict__ s0, const float* __restrict__ s1,
    const float* __restrict__ s2, const float* __restrict__ s3,
    ushort* __restrict__ o0, ushort* __restrict__ o1,
    ushort* __restrict__ o2, ushort* __restrict__ o3, int n)
{
  const float* s; ushort* o;
  switch (blockIdx.y) {
    case 0: s = s0; o = o0; break;
    case 1: s = s1; o = o1; break;
    case 2: s = s2; o = o2; break;
    default: s = s3; o = o3; break;
  }
  int stride = gridDim.x * 1024;
  for (int i = (blockIdx.x * 256 + threadIdx.x) * 4; i < n; i += stride) {
    float4 v = *(const float4*)(s + i);
    ushort4 u;
    u.x = f2bf(v.x); u.y = f2bf(v.y); u.z = f2bf(v.z); u.w = f2bf(v.w);
    *(ushort4*)(o + i) = u;
  }
}

// ---------------- QKV projection GEMM, split-K, fp32-A fused convert ----------------
// C[2048,512] = A[2048,4096](fp32) * W[512,4096]^T(bf16) for 3 (A,W) pairs.
// A is read fp32 from the original inputs, converted in-register to bf16, and
// ds_written to LDS. B uses global_load_lds from pre-packed bf16 weights.
__global__ __launch_bounds__(256) void gemm_qkv(
    const float* __restrict__ aq, const float* __restrict__ ak, const float* __restrict__ av,
    const ushort* __restrict__ wq, const ushort* __restrict__ wk, const ushort* __restrict__ wv,
    float* __restrict__ part, int lgs)
{
  __shared__ __align__(16) ushort At[128 * 64];
  __shared__ __align__(16) ushort Bt[128 * 64];
  int z = blockIdx.z;
  int g = z >> lgs, s = z & ((1 << lgs) - 1);
  const float* A; const ushort* Bm;
  if (g == 0)      { A = aq; Bm = wq; }
  else if (g == 1) { A = ak; Bm = wk; }
  else             { A = av; Bm = wv; }
  float* Pd = part + ((size_t)z) * 1048576;   // plane 2048*512
  const int K = 4096;
  const int kchunk = K >> lgs;
  const int k0 = s * kchunk, kend = k0 + kchunk;
  int rowBase = blockIdx.x * 128;   // 16 blocks -> 2048 rows
  int colBase = blockIdx.y * 128;   // 4 blocks  -> 512 cols
  int tid = threadIdx.x, l = tid & 63, w = tid >> 6;
  int wr = w >> 1, wc = w & 1, fr = l & 15, fq = l >> 4;
  // A staging map: thread t owns At elems [t*32, t*32+32) = row t/2, cols (t&1)*32..+32
  const float* Aptr = A + (size_t)(rowBase + (tid >> 1)) * K + (tid & 1) * 32;
  f32x4 acc[4][4];
#pragma unroll
  for (int m = 0; m < 4; ++m)
#pragma unroll
    for (int n = 0; n < 4; ++n) acc[m][n] = (f32x4){0.f, 0.f, 0.f, 0.f};

  float4 areg[8];
#pragma unroll
  for (int j = 0; j < 8; ++j) areg[j] = *(const float4*)(Aptr + k0 + j * 4);

  for (int kt = k0; kt < kend; kt += 64) {
    // B stage (bf16 weights, direct to LDS)
#pragma unroll
    for (int j = 0; j < 4; ++j) {
      int c = ((w * 4 + j) << 6) + l;
      int row = c >> 3, cc = c & 7;
      __builtin_amdgcn_global_load_lds(AS1(Bm + (size_t)(colBase + row) * K + kt + cc * 8),
                                       AS3((char*)Bt + (w * 4 + j) * 1024), 16, 0, 0);
    }
    // convert A regs (loaded last iteration / prologue) -> LDS bf16
    uint32_t cp[16];
#pragma unroll
    for (int j = 0; j < 8; ++j) {
      uint32_t lo, hi;
      asm volatile("v_cvt_pk_bf16_f32 %0, %1, %2" : "=v"(lo) : "v"(areg[j].x), "v"(areg[j].y));
      asm volatile("v_cvt_pk_bf16_f32 %0, %1, %2" : "=v"(hi) : "v"(areg[j].z), "v"(areg[j].w));
      cp[2 * j] = lo; cp[2 * j + 1] = hi;
    }
    uint32_t* dstA = (uint32_t*)((char*)At + tid * 64);
#pragma unroll
    for (int k2 = 0; k2 < 4; ++k2)
      ((uint4*)dstA)[k2] = make_uint4(cp[4 * k2], cp[4 * k2 + 1], cp[4 * k2 + 2], cp[4 * k2 + 3]);
    // prefetch next A chunk (drained by the barrier alongside B's gload_lds)
    if (kt + 64 < kend) {
#pragma unroll
      for (int j = 0; j < 8; ++j) areg[j] = *(const float4*)(Aptr + kt + 64 + j * 4);
    }
    __syncthreads();
#pragma unroll
    for (int kc = 0; kc < 2; ++kc) {
      bf16x8 af[4], bfv[4];
#pragma unroll
      for (int m = 0; m < 4; ++m)
        af[m] = *(const bf16x8*)&At[(wr * 64 + m * 16 + fr) * 64 + kc * 32 + fq * 8];
#pragma unroll
      for (int n = 0; n < 4; ++n)
        bfv[n] = *(const bf16x8*)&Bt[(wc * 64 + n * 16 + fr) * 64 + kc * 32 + fq * 8];
#pragma unroll
      for (int m = 0; m < 4; ++m)
#pragma unroll
        for (int n = 0; n < 4; ++n)
          acc[m][n] = __builtin_amdgcn_mfma_f32_16x16x32_bf16(af[m], bfv[n], acc[m][n], 0, 0, 0);
    }
    __syncthreads();
  }
#pragma unroll
  for (int m = 0; m < 4; ++m)
#pragma unroll
    for (int n = 0; n < 4; ++n)
#pragma unroll
      for (int r = 0; r < 4; ++r) {
        int row = rowBase + wr * 64 + m * 16 + fq * 4 + r;
        int col = colBase + wc * 64 + n * 16 + fr;
        Pd[(size_t)row * 512 + col] = acc[m][n][r];
      }
}

// ---------------- reduce split-K partials -> bf16 Q/K/V ----------------
__global__ __launch_bounds__(256) void reduce_qkv(
    const float* __restrict__ part, ushort* __restrict__ Qp, ushort* __restrict__ Kp,
    ushort* __restrict__ Vp, int lgs)
{
  int g = blockIdx.y;
  ushort* dst = g == 0 ? Qp : (g == 1 ? Kp : Vp);
  const float* p = part + (((size_t)g) << lgs) * 1048576;
  int i = (blockIdx.x * 256 + threadIdx.x) * 4;
  float4 acc = *(const float4*)(p + i);
  int splits = 1 << lgs;
  for (int s = 1; s < splits; ++s) {
    float4 b = *(const float4*)(p + (size_t)s * 1048576 + i);
    acc.x += b.x; acc.y += b.y; acc.z += b.z; acc.w += b.w;
  }
  ushort4 u;
  u.x = f2bf(acc.x); u.y = f2bf(acc.y); u.z = f2bf(acc.z); u.w = f2bf(acc.w);
  *(ushort4*)(dst + i) = u;
}

// ---------------- attention: per (b,h, row-half) block ----------------
__global__ __launch_bounds__(256) void attn(
    const ushort* __restrict__ Qp, const ushort* __restrict__ Kp, const ushort* __restrict__ Vp,
    float* __restrict__ Obuf, const float* __restrict__ temp)
{
  __shared__ __align__(16) ushort Qs[64 * 64];    // [crow][d]
  __shared__ __align__(16) ushort Ks[128 * 64];   // [e][d]
  __shared__ __align__(16) ushort Vt[64 * 128];   // [d][e] (transposed)
  __shared__ __align__(16) float  Sl[64 * 128];   // scores
  __shared__ __align__(16) ushort Pl[64 * 128];   // exp(S-max) bf16
  __shared__ float rsum[64];
  int bh = blockIdx.y, b = bh >> 3, h = bh & 7;
  int c0 = blockIdx.x * 64;
  int tid = threadIdx.x, l = tid & 63, w = tid >> 6;
  int wr = w >> 1, wc = w & 1, fr = l & 15, fq = l >> 4;
  float invT = 1.0f / temp[0];
  const size_t rowQ = (size_t)(b * 128 + c0);

  // stage Q (64 rows x 64 d)
#pragma unroll
  for (int j = 0; j < 2; ++j) {
    int c = ((w * 2 + j) << 6) + l, row = c >> 3, cc = c & 7;
    __builtin_amdgcn_global_load_lds(AS1(Qp + (rowQ + row) * 512 + h * 64 + cc * 8),
                                     AS3((char*)Qs + (w * 2 + j) * 1024), 16, 0, 0);
  }
  // stage K (128 rows x 64 d)
#pragma unroll
  for (int j = 0; j < 4; ++j) {
    int c = ((w * 4 + j) << 6) + l, row = c >> 3, cc = c & 7;
    __builtin_amdgcn_global_load_lds(AS1(Kp + (size_t)(b * 128 + row) * 512 + h * 64 + cc * 8),
                                     AS3((char*)Ks + (w * 4 + j) * 1024), 16, 0, 0);
  }
  // stage V transposed: Vt[d][e]
#pragma unroll
  for (int t = 0; t < 4; ++t) {
    int ch = tid + t * 256, e = ch >> 3, d0 = (ch & 7) * 8;
    bf16x8 vv = *(const bf16x8*)(Vp + (size_t)(b * 128 + e) * 512 + h * 64 + d0);
#pragma unroll
    for (int j = 0; j < 8; ++j) Vt[(d0 + j) * 128 + e] = (ushort)vv[j];
  }
  __syncthreads();

  // S = Q*K^T (64x128)
  f32x4 sa[2][4];
#pragma unroll
  for (int m = 0; m < 2; ++m)
#pragma unroll
    for (int n = 0; n < 4; ++n) sa[m][n] = (f32x4){0.f, 0.f, 0.f, 0.f};
#pragma unroll
  for (int kc = 0; kc < 2; ++kc) {
    bf16x8 aQ[2], bK[4];
#pragma unroll
    for (int m = 0; m < 2; ++m)
      aQ[m] = *(const bf16x8*)&Qs[(wr * 32 + m * 16 + fr) * 64 + kc * 32 + fq * 8];
#pragma unroll
    for (int n = 0; n < 4; ++n)
      bK[n] = *(const bf16x8*)&Ks[(wc * 64 + n * 16 + fr) * 64 + kc * 32 + fq * 8];
#pragma unroll
    for (int m = 0; m < 2; ++m)
#pragma unroll
      for (int n = 0; n < 4; ++n)
        sa[m][n] = __builtin_amdgcn_mfma_f32_16x16x32_bf16(aQ[m], bK[n], sa[m][n], 0, 0, 0);
  }
#pragma unroll
  for (int m = 0; m < 2; ++m)
#pragma unroll
    for (int n = 0; n < 4; ++n)
#pragma unroll
      for (int r = 0; r < 4; ++r)
        Sl[(wr * 32 + m * 16 + fq * 4 + r) * 128 + wc * 64 + n * 16 + fr] = sa[m][n][r] * invT;
  __syncthreads();

  // softmax: 4 threads per row, 32 cols each
  {
    int row = tid >> 2, qq = tid & 3;
    const float* srow = Sl + row * 128 + qq * 32;
    float4 va[8];
#pragma unroll
    for (int i = 0; i < 8; ++i) va[i] = *(const float4*)(srow + i * 4);
    float mx = -1e30f;
#pragma unroll
    for (int i = 0; i < 8; ++i)
      mx = fmaxf(mx, fmaxf(fmaxf(va[i].x, va[i].y), fmaxf(va[i].z, va[i].w)));
    mx = fmaxf(mx, __shfl_xor(mx, 1));
    mx = fmaxf(mx, __shfl_xor(mx, 2));
    float ssum = 0.f;
    ushort* prow = Pl + row * 128 + qq * 32;
#pragma unroll
    for (int i = 0; i < 8; ++i) {
      float e0 = __expf(va[i].x - mx), e1 = __expf(va[i].y - mx);
      float e2 = __expf(va[i].z - mx), e3 = __expf(va[i].w - mx);
      ssum += (e0 + e1) + (e2 + e3);
      ushort4 u; u.x = f2bf(e0); u.y = f2bf(e1); u.z = f2bf(e2); u.w = f2bf(e3);
      *(ushort4*)(prow + i * 4) = u;
    }
    ssum += __shfl_xor(ssum, 1);
    ssum += __shfl_xor(ssum, 2);
    if (qq == 0) rsum[row] = ssum;
  }
  __syncthreads();

  // O = P*V (64x64)
  f32x4 oa[2][2];
#pragma unroll
  for (int m = 0; m < 2; ++m)
#pragma unroll
    for (int n = 0; n < 2; ++n) oa[m][n] = (f32x4){0.f, 0.f, 0.f, 0.f};
#pragma unroll
  for (int kc = 0; kc < 4; ++kc) {
    bf16x8 aP[2], bV[2];
#pragma unroll
    for (int m = 0; m < 2; ++m)
      aP[m] = *(const bf16x8*)&Pl[(wr * 32 + m * 16 + fr) * 128 + kc * 32 + fq * 8];
#pragma unroll
    for (int n = 0; n < 2; ++n)
      bV[n] = *(const bf16x8*)&Vt[(wc * 32 + n * 16 + fr) * 128 + kc * 32 + fq * 8];
#pragma unroll
    for (int m = 0; m < 2; ++m)
#pragma unroll
      for (int n = 0; n < 2; ++n)
        oa[m][n] = __builtin_amdgcn_mfma_f32_16x16x32_bf16(aP[m], bV[n], oa[m][n], 0, 0, 0);
  }
#pragma unroll
  for (int m = 0; m < 2; ++m)
#pragma unroll
    for (int n = 0; n < 2; ++n)
#pragma unroll
      for (int r = 0; r < 4; ++r) {
        int row = wr * 32 + m * 16 + fq * 4 + r, col = wc * 32 + n * 16 + fr;
        Obuf[(rowQ + row) * 512 + h * 64 + col] = oa[m][n][r] / rsum[row];
      }
}

// ---------------- swish + LayerNorm over D=512 (wave per row), out bf16 ----------------
__global__ __launch_bounds__(256) void swish_ln(
    const float* __restrict__ O, ushort* __restrict__ X,
    const float* __restrict__ gamma, const float* __restrict__ beta)
{
  int row = blockIdx.x * 4 + (threadIdx.x >> 6);
  int lane = threadIdx.x & 63;
  const float* x = O + (size_t)row * 512 + lane * 8;
  float4 va = *(const float4*)(x);
  float4 vb = *(const float4*)(x + 4);
  float y[8] = {va.x, va.y, va.z, va.w, vb.x, vb.y, vb.z, vb.w};
  float s = 0.f, sq = 0.f;
#pragma unroll
  for (int i = 0; i < 8; ++i) {
    y[i] = y[i] / (1.f + __expf(-y[i]));
    s += y[i]; sq += y[i] * y[i];
  }
#pragma unroll
  for (int o = 1; o < 64; o <<= 1) { s += __shfl_xor(s, o); sq += __shfl_xor(sq, o); }
  float mean = s * (1.f / 512.f);
  float var = (sq - s * mean) * (1.f / 511.f);   // unbiased (ddof=1)
  float inv = 1.f / (sqrtf(var) + 1e-6f);
  const float4 g0 = *(const float4*)(gamma + lane * 8);
  const float4 g1 = *(const float4*)(gamma + lane * 8 + 4);
  const float4 b0 = *(const float4*)(beta + lane * 8);
  const float4 b1 = *(const float4*)(beta + lane * 8 + 4);
  float gg[8] = {g0.x, g0.y, g0.z, g0.w, g1.x, g1.y, g1.z, g1.w};
  float bb[8] = {b0.x, b0.y, b0.z, b0.w, b1.x, b1.y, b1.z, b1.w};
  ushort u[8];
#pragma unroll
  for (int i = 0; i < 8; ++i) u[i] = f2bf(gg[i] * (y[i] - mean) * inv + bb[i]);
  *(uint4*)(X + (size_t)row * 512 + lane * 8) = *(uint4*)u;
}

// ---------------- fc GEMM + residual + BN partial sums ----------------
__global__ __launch_bounds__(256) void gemm_fc(
    const ushort* __restrict__ A, const ushort* __restrict__ Bm,
    const float* __restrict__ resid, float* __restrict__ out,
    float* __restrict__ bn_sum, float* __restrict__ bn_sq)
{
  __shared__ __align__(16) ushort At[128 * 64];
  __shared__ __align__(16) ushort Bt[128 * 64];
  __shared__ float csum[128], csq[128];
  const int K = 512;
  int rowBase = blockIdx.x * 128;   // 16
  int colBase = blockIdx.y * 128;   // 32
  int tid = threadIdx.x, l = tid & 63, w = tid >> 6;
  int wr = w >> 1, wc = w & 1, fr = l & 15, fq = l >> 4;
  if (tid < 128) { csum[tid] = 0.f; csq[tid] = 0.f; }
  f32x4 acc[4][4];
#pragma unroll
  for (int m = 0; m < 4; ++m)
#pragma unroll
    for (int n = 0; n < 4; ++n) acc[m][n] = (f32x4){0.f, 0.f, 0.f, 0.f};

  for (int kt = 0; kt < K; kt += 64) {
#pragma unroll
    for (int j = 0; j < 4; ++j) {
      int c = ((w * 4 + j) << 6) + l;
      int row = c >> 3, cc = c & 7;
      __builtin_amdgcn_global_load_lds(AS1(A + (size_t)(rowBase + row) * K + kt + cc * 8),
                                       AS3((char*)At + (w * 4 + j) * 1024), 16, 0, 0);
      __builtin_amdgcn_global_load_lds(AS1(Bm + (size_t)(colBase + row) * K + kt + cc * 8),
                                       AS3((char*)Bt + (w * 4 + j) * 1024), 16, 0, 0);
    }
    __syncthreads();
#pragma unroll
    for (int kc = 0; kc < 2; ++kc) {
      bf16x8 af[4], bfv[4];
#pragma unroll
      for (int m = 0; m < 4; ++m)
        af[m] = *(const bf16x8*)&At[(wr * 64 + m * 16 + fr) * 64 + kc * 32 + fq * 8];
#pragma unroll
      for (int n = 0; n < 4; ++n)
        bfv[n] = *(const bf16x8*)&Bt[(wc * 64 + n * 16 + fr) * 64 + kc * 32 + fq * 8];
#pragma unroll
      for (int m = 0; m < 4; ++m)
#pragma unroll
        for (int n = 0; n < 4; ++n)
          acc[m][n] = __builtin_amdgcn_mfma_f32_16x16x32_bf16(af[m], bfv[n], acc[m][n], 0, 0, 0);
    }
    __syncthreads();
  }
  // epilogue: out = acc + residual; per-channel partial sums for BN
#pragma unroll
  for (int m = 0; m < 4; ++m)
#pragma unroll
    for (int r = 0; r < 4; ++r) {
      float ps = 0.f, pq = 0.f;
#pragma unroll
      for (int n = 0; n < 4; ++n) {
        int row = rowBase + wr * 64 + m * 16 + fq * 4 + r;
        int col = colBase + wc * 64 + n * 16 + fr;
        size_t idx = (size_t)row * 4096 + col;
        float val = acc[m][n][r] + resid[idx];
        out[idx] = val;
        ps += val; pq += val * val;
      }
#pragma unroll
      for (int o = 1; o < 16; o <<= 1) { ps += __shfl_xor(ps, o); pq += __shfl_xor(pq, o); }
      if (fr == 0) {
        int ch = wr * 64 + m * 16 + fq * 4 + r;   // rowBase % 128 == 0
        atomicAdd(&csum[ch], ps);
        atomicAdd(&csq[ch], pq);
      }
    }
  __syncthreads();
  if (tid < 128) {
    atomicAdd(&bn_sum[tid], csum[tid]);
    atomicAdd(&bn_sq[tid], csq[tid]);
  }
}

// ---------------- BatchNorm finalize (in place on d_out) ----------------
__global__ __launch_bounds__(256) void bn_norm(
    float* __restrict__ out, const float* __restrict__ bn_sum, const float* __restrict__ bn_sq,
    const float* __restrict__ gamma, const float* __restrict__ beta)
{
  const float inv_n = 1.f / 65536.f;
  int stride = gridDim.x * blockDim.x;
  for (int v = blockIdx.x * blockDim.x + threadIdx.x; v < 2097152; v += stride) {
    int elem = v * 4;
    int ch = (elem >> 12) & 127;
    float mean = bn_sum[ch] * inv_n;
    float var = bn_sq[ch] * inv_n - mean * mean;
    float g = gamma[ch] * rsqrtf(var + 1e-5f);
    float bta = beta[ch];
    float4 x = *(float4*)(out + elem);
    x.x = (x.x - mean) * g + bta;
    x.y = (x.y - mean) * g + bta;
    x.z = (x.z - mean) * g + bta;
    x.w = (x.w - mean) * g + bta;
    *(float4*)(out + elem) = x;
  }
}

extern "C" void kernel_launch(void* const* d_in, const int* in_sizes, int n_in,
                              void* d_out, int out_size, void* d_ws, size_t ws_size,
                              hipStream_t stream)
{
  const float* v_in = (const float*)d_in[0];
  const float* k_in = (const float*)d_in[1];
  const float* q_in = (const float*)d_in[2];
  const float* w_qs = (const float*)d_in[3];
  const float* w_ks = (const float*)d_in[4];
  const float* w_vs = (const float*)d_in[5];
  const float* w_fc = (const float*)d_in[6];
  const float* ln_g = (const float*)d_in[7];
  const float* ln_b = (const float*)d_in[8];
  const float* temp = (const float*)d_in[9];
  const float* bn_g = (const float*)d_in[10];
  const float* bn_b = (const float*)d_in[11];
  float* out = (float*)d_out;

  char* ws = (char*)d_ws;
  size_t off = 0;
  auto alloc = [&](size_t bytes) { char* p = ws + off; off += bytes; return p; };
  ushort* wq  = (ushort*)alloc(512ull * 4096 * 2);
  ushort* wk  = (ushort*)alloc(512ull * 4096 * 2);
  ushort* wv  = (ushort*)alloc(512ull * 4096 * 2);
  ushort* wfc = (ushort*)alloc(512ull * 4096 * 2);
  ushort* Qp  = (ushort*)alloc(2048ull * 512 * 2);
  ushort* Kp  = (ushort*)alloc(2048ull * 512 * 2);
  ushort* Vp  = (ushort*)alloc(2048ull * 512 * 2);
  float*  Obuf= (float*)alloc(2048ull * 512 * 4);
  ushort* X16 = (ushort*)alloc(2048ull * 512 * 2);
  float*  bns = (float*)alloc(128 * 4);
  float*  bnq = (float*)alloc(128 * 4);

  // split-K partial planes: 3*(1<<lgs) planes of 2048*512 fp32
  int lgs = 2;                       // 4-way split-K -> 768 blocks (~3 blocks/CU)
  if (off + (3ull << lgs) * 1048576 * 4 > ws_size) lgs = 1;
  if (off + (3ull << lgs) * 1048576 * 4 > ws_size) lgs = 0;
  float* part = (float*)alloc((3ull << lgs) * 1048576 * 4);

  hipMemsetAsync(bns, 0, 256 * 4, stream);   // zero bns+bnq (adjacent)

  pack4<<<dim3(512, 4), 256, 0, stream>>>(w_qs, w_ks, w_vs, w_fc, wq, wk, wv, wfc,
                                          512 * 4096);
  gemm_qkv<<<dim3(16, 4, 3 << lgs), 256, 0, stream>>>(q_in, k_in, v_in, wq, wk, wv, part, lgs);
  reduce_qkv<<<dim3(1024, 3), 256, 0, stream>>>(part, Qp, Kp, Vp, lgs);
  attn<<<dim3(2, 128), 256, 0, stream>>>(Qp, Kp, Vp, Obuf, temp);
  swish_ln<<<512, 256, 0, stream>>>(Obuf, X16, ln_g, ln_b);
  gemm_fc<<<dim3(16, 32), 256, 0, stream>>>(X16, wfc, v_in, out, bns, bnq);
  bn_norm<<<2048, 256, 0, stream>>>(out, bns, bnq, bn_g, bn_b);
}

// Round 4
// 148.956 us; speedup vs baseline: 1.1901x; 1.0111x over previous
//
#include <hip/hip_runtime.h>
#include <hip/hip_bf16.h>
#include <stdint.h>

typedef __attribute__((ext_vector_type(8))) short bf16x8;
typedef __attribute__((ext_vector_type(4))) float f32x4;

#define AS1(p) ((const __attribute__((address_space(1))) uint32_t*)(p))
#define AS3(p) ((__attribute__((address_space(3))) uint32_t*)(p))

__device__ __forceinline__ ushort f2bf(float f) {
  uint32_t u = __float_as_uint(f);
  uint32_t r = (u + 0x7fffu + ((u >> 16) & 1u)) >> 16;
  return (ushort)r;
}

// ---------------- pack: fp32 -> bf16 (weights only) ----------------
__global__ __launch_bounds__(256) void pack4(
    const float* __restrict__ s0, const float* __restrict__ s1,
    const float* __restrict__ s2, const float* __restrict__ s3,
    ushort* __restrict__ o0, ushort* __restrict__ o1,
    ushort* __restrict__ o2, ushort* __restrict__ o3, int n)
{
  const float* s; ushort* o;
  switch (blockIdx.y) {
    case 0: s = s0; o = o0; break;
    case 1: s = s1; o = o1; break;
    case 2: s = s2; o = o2; break;
    default: s = s3; o = o3; break;
  }
  int stride = gridDim.x * 1024;
  for (int i = (blockIdx.x * 256 + threadIdx.x) * 4; i < n; i += stride) {
    float4 v = *(const float4*)(s + i);
    ushort4 u;
    u.x = f2bf(v.x); u.y = f2bf(v.y); u.z = f2bf(v.z); u.w = f2bf(v.w);
    *(ushort4*)(o + i) = u;
  }
}

// ---------------- QKV projection GEMM, split-K, fp32-A fused convert ----------------
// C[2048,512] = A[2048,4096](fp32) * W[512,4096]^T(bf16) for 3 (A,W) pairs.
// A staging: thread t owns LDS 16B-chunks {t, t+256, t+512, t+768} -> per-k2
// ds_write_b128 is lane-contiguous (conflict-free); global loads are 8 lanes/row
// x 32B contiguous. Register double-buffer (bufA/bufB) gives the loads a full
// K-step of latency cover. B uses global_load_lds from pre-packed bf16 weights.
__global__ __launch_bounds__(256) void gemm_qkv(
    const float* __restrict__ aq, const float* __restrict__ ak, const float* __restrict__ av,
    const ushort* __restrict__ wq, const ushort* __restrict__ wk, const ushort* __restrict__ wv,
    float* __restrict__ part, int lgs)
{
  __shared__ __align__(16) ushort At[128 * 64];
  __shared__ __align__(16) ushort Bt[128 * 64];
  int z = blockIdx.z;
  int g = z >> lgs, s = z & ((1 << lgs) - 1);
  const float* A; const ushort* Bm;
  if (g == 0)      { A = aq; Bm = wq; }
  else if (g == 1) { A = ak; Bm = wk; }
  else             { A = av; Bm = wv; }
  float* Pd = part + ((size_t)z) * 1048576;   // plane 2048*512
  const int K = 4096;
  const int kchunk = K >> lgs;                // multiple of 128 for lgs<=5
  const int k0 = s * kchunk, kend = k0 + kchunk;
  int rowBase = blockIdx.x * 128;   // 16 blocks -> 2048 rows
  int colBase = blockIdx.y * 128;   // 4 blocks  -> 512 cols
  int tid = threadIdx.x, l = tid & 63, w = tid >> 6;
  int wr = w >> 1, wc = w & 1, fr = l & 15, fq = l >> 4;
  // A chunk c = k2*256 + tid -> LDS row c>>3, cols (c&7)*8; global row k2*32+(tid>>3)
  const float* Arow = A + (size_t)(rowBase + (tid >> 3)) * K + (tid & 7) * 8;

  f32x4 acc[4][4];
#pragma unroll
  for (int m = 0; m < 4; ++m)
#pragma unroll
    for (int n = 0; n < 4; ++n) acc[m][n] = (f32x4){0.f, 0.f, 0.f, 0.f};

  float4 bufA[4][2], bufB[4][2];

  auto loadA = [&](float4 (&buf)[4][2], int ktn) {
#pragma unroll
    for (int k2 = 0; k2 < 4; ++k2) {
      const float* p = Arow + (size_t)k2 * 32 * K + ktn;
      buf[k2][0] = *(const float4*)p;
      buf[k2][1] = *(const float4*)(p + 4);
    }
  };
  auto cvtWrite = [&](float4 (&buf)[4][2]) {
#pragma unroll
    for (int k2 = 0; k2 < 4; ++k2) {
      uint32_t u0, u1, u2, u3;
      asm("v_cvt_pk_bf16_f32 %0, %1, %2" : "=v"(u0) : "v"(buf[k2][0].x), "v"(buf[k2][0].y));
      asm("v_cvt_pk_bf16_f32 %0, %1, %2" : "=v"(u1) : "v"(buf[k2][0].z), "v"(buf[k2][0].w));
      asm("v_cvt_pk_bf16_f32 %0, %1, %2" : "=v"(u2) : "v"(buf[k2][1].x), "v"(buf[k2][1].y));
      asm("v_cvt_pk_bf16_f32 %0, %1, %2" : "=v"(u3) : "v"(buf[k2][1].z), "v"(buf[k2][1].w));
      *(uint4*)((char*)At + (k2 * 256 + tid) * 16) = make_uint4(u0, u1, u2, u3);
    }
  };
  auto stageB = [&](int ktn) {
#pragma unroll
    for (int j = 0; j < 4; ++j) {
      int c = ((w * 4 + j) << 6) + l;
      int row = c >> 3, cc = c & 7;
      __builtin_amdgcn_global_load_lds(AS1(Bm + (size_t)(colBase + row) * K + ktn + cc * 8),
                                       AS3((char*)Bt + (w * 4 + j) * 1024), 16, 0, 0);
    }
  };
  auto mfmaPhase = [&]() {
#pragma unroll
    for (int kc = 0; kc < 2; ++kc) {
      bf16x8 af[4], bfv[4];
#pragma unroll
      for (int m = 0; m < 4; ++m)
        af[m] = *(const bf16x8*)&At[(wr * 64 + m * 16 + fr) * 64 + kc * 32 + fq * 8];
#pragma unroll
      for (int n = 0; n < 4; ++n)
        bfv[n] = *(const bf16x8*)&Bt[(wc * 64 + n * 16 + fr) * 64 + kc * 32 + fq * 8];
#pragma unroll
      for (int m = 0; m < 4; ++m)
#pragma unroll
        for (int n = 0; n < 4; ++n)
          acc[m][n] = __builtin_amdgcn_mfma_f32_16x16x32_bf16(af[m], bfv[n], acc[m][n], 0, 0, 0);
    }
  };

  loadA(bufA, k0);
  for (int kt = k0; kt < kend; kt += 128) {
    if (kt + 64 < kend) loadA(bufB, kt + 64);
    stageB(kt);
    cvtWrite(bufA);
    __syncthreads();
    mfmaPhase();
    __syncthreads();
    if (kt + 128 < kend) loadA(bufA, kt + 128);
    stageB(kt + 64);
    cvtWrite(bufB);
    __syncthreads();
    mfmaPhase();
    __syncthreads();
  }

#pragma unroll
  for (int m = 0; m < 4; ++m)
#pragma unroll
    for (int n = 0; n < 4; ++n)
#pragma unroll
      for (int r = 0; r < 4; ++r) {
        int row = rowBase + wr * 64 + m * 16 + fq * 4 + r;
        int col = colBase + wc * 64 + n * 16 + fr;
        Pd[(size_t)row * 512 + col] = acc[m][n][r];
      }
}

// ---------------- reduce split-K partials -> bf16 Q/K/V ----------------
__global__ __launch_bounds__(256) void reduce_qkv(
    const float* __restrict__ part, ushort* __restrict__ Qp, ushort* __restrict__ Kp,
    ushort* __restrict__ Vp, int lgs)
{
  int g = blockIdx.y;
  ushort* dst = g == 0 ? Qp : (g == 1 ? Kp : Vp);
  const float* p = part + (((size_t)g) << lgs) * 1048576;
  int i = (blockIdx.x * 256 + threadIdx.x) * 4;
  float4 acc = *(const float4*)(p + i);
  int splits = 1 << lgs;
  for (int s = 1; s < splits; ++s) {
    float4 b = *(const float4*)(p + (size_t)s * 1048576 + i);
    acc.x += b.x; acc.y += b.y; acc.z += b.z; acc.w += b.w;
  }
  ushort4 u;
  u.x = f2bf(acc.x); u.y = f2bf(acc.y); u.z = f2bf(acc.z); u.w = f2bf(acc.w);
  *(ushort4*)(dst + i) = u;
}

// ---------------- attention: per (b,h, row-half) block ----------------
__global__ __launch_bounds__(256) void attn(
    const ushort* __restrict__ Qp, const ushort* __restrict__ Kp, const ushort* __restrict__ Vp,
    float* __restrict__ Obuf, const float* __restrict__ temp)
{
  __shared__ __align__(16) ushort Qs[64 * 64];    // [crow][d]
  __shared__ __align__(16) ushort Ks[128 * 64];   // [e][d]
  __shared__ __align__(16) ushort Vt[64 * 128];   // [d][e] (transposed)
  __shared__ __align__(16) float  Sl[64 * 128];   // scores
  __shared__ __align__(16) ushort Pl[64 * 128];   // exp(S-max) bf16
  __shared__ float rsum[64];
  int bh = blockIdx.y, b = bh >> 3, h = bh & 7;
  int c0 = blockIdx.x * 64;
  int tid = threadIdx.x, l = tid & 63, w = tid >> 6;
  int wr = w >> 1, wc = w & 1, fr = l & 15, fq = l >> 4;
  float invT = 1.0f / temp[0];
  const size_t rowQ = (size_t)(b * 128 + c0);

  // stage Q (64 rows x 64 d)
#pragma unroll
  for (int j = 0; j < 2; ++j) {
    int c = ((w * 2 + j) << 6) + l, row = c >> 3, cc = c & 7;
    __builtin_amdgcn_global_load_lds(AS1(Qp + (rowQ + row) * 512 + h * 64 + cc * 8),
                                     AS3((char*)Qs + (w * 2 + j) * 1024), 16, 0, 0);
  }
  // stage K (128 rows x 64 d)
#pragma unroll
  for (int j = 0; j < 4; ++j) {
    int c = ((w * 4 + j) << 6) + l, row = c >> 3, cc = c & 7;
    __builtin_amdgcn_global_load_lds(AS1(Kp + (size_t)(b * 128 + row) * 512 + h * 64 + cc * 8),
                                     AS3((char*)Ks + (w * 4 + j) * 1024), 16, 0, 0);
  }
  // stage V transposed: Vt[d][e]
#pragma unroll
  for (int t = 0; t < 4; ++t) {
    int ch = tid + t * 256, e = ch >> 3, d0 = (ch & 7) * 8;
    bf16x8 vv = *(const bf16x8*)(Vp + (size_t)(b * 128 + e) * 512 + h * 64 + d0);
#pragma unroll
    for (int j = 0; j < 8; ++j) Vt[(d0 + j) * 128 + e] = (ushort)vv[j];
  }
  __syncthreads();

  // S = Q*K^T (64x128)
  f32x4 sa[2][4];
#pragma unroll
  for (int m = 0; m < 2; ++m)
#pragma unroll
    for (int n = 0; n < 4; ++n) sa[m][n] = (f32x4){0.f, 0.f, 0.f, 0.f};
#pragma unroll
  for (int kc = 0; kc < 2; ++kc) {
    bf16x8 aQ[2], bK[4];
#pragma unroll
    for (int m = 0; m < 2; ++m)
      aQ[m] = *(const bf16x8*)&Qs[(wr * 32 + m * 16 + fr) * 64 + kc * 32 + fq * 8];
#pragma unroll
    for (int n = 0; n < 4; ++n)
      bK[n] = *(const bf16x8*)&Ks[(wc * 64 + n * 16 + fr) * 64 + kc * 32 + fq * 8];
#pragma unroll
    for (int m = 0; m < 2; ++m)
#pragma unroll
      for (int n = 0; n < 4; ++n)
        sa[m][n] = __builtin_amdgcn_mfma_f32_16x16x32_bf16(aQ[m], bK[n], sa[m][n], 0, 0, 0);
  }
#pragma unroll
  for (int m = 0; m < 2; ++m)
#pragma unroll
    for (int n = 0; n < 4; ++n)
#pragma unroll
      for (int r = 0; r < 4; ++r)
        Sl[(wr * 32 + m * 16 + fq * 4 + r) * 128 + wc * 64 + n * 16 + fr] = sa[m][n][r] * invT;
  __syncthreads();

  // softmax: 4 threads per row, 32 cols each
  {
    int row = tid >> 2, qq = tid & 3;
    const float* srow = Sl + row * 128 + qq * 32;
    float4 va[8];
#pragma unroll
    for (int i = 0; i < 8; ++i) va[i] = *(const float4*)(srow + i * 4);
    float mx = -1e30f;
#pragma unroll
    for (int i = 0; i < 8; ++i)
      mx = fmaxf(mx, fmaxf(fmaxf(va[i].x, va[i].y), fmaxf(va[i].z, va[i].w)));
    mx = fmaxf(mx, __shfl_xor(mx, 1));
    mx = fmaxf(mx, __shfl_xor(mx, 2));
    float ssum = 0.f;
    ushort* prow = Pl + row * 128 + qq * 32;
#pragma unroll
    for (int i = 0; i < 8; ++i) {
      float e0 = __expf(va[i].x - mx), e1 = __expf(va[i].y - mx);
      float e2 = __expf(va[i].z - mx), e3 = __expf(va[i].w - mx);
      ssum += (e0 + e1) + (e2 + e3);
      ushort4 u; u.x = f2bf(e0); u.y = f2bf(e1); u.z = f2bf(e2); u.w = f2bf(e3);
      *(ushort4*)(prow + i * 4) = u;
    }
    ssum += __shfl_xor(ssum, 1);
    ssum += __shfl_xor(ssum, 2);
    if (qq == 0) rsum[row] = ssum;
  }
  __syncthreads();

  // O = P*V (64x64)
  f32x4 oa[2][2];
#pragma unroll
  for (int m = 0; m < 2; ++m)
#pragma unroll
    for (int n = 0; n < 2; ++n) oa[m][n] = (f32x4){0.f, 0.f, 0.f, 0.f};
#pragma unroll
  for (int kc = 0; kc < 4; ++kc) {
    bf16x8 aP[2], bV[2];
#pragma unroll
    for (int m = 0; m < 2; ++m)
      aP[m] = *(const bf16x8*)&Pl[(wr * 32 + m * 16 + fr) * 128 + kc * 32 + fq * 8];
#pragma unroll
    for (int n = 0; n < 2; ++n)
      bV[n] = *(const bf16x8*)&Vt[(wc * 32 + n * 16 + fr) * 128 + kc * 32 + fq * 8];
#pragma unroll
    for (int m = 0; m < 2; ++m)
#pragma unroll
      for (int n = 0; n < 2; ++n)
        oa[m][n] = __builtin_amdgcn_mfma_f32_16x16x32_bf16(aP[m], bV[n], oa[m][n], 0, 0, 0);
  }
#pragma unroll
  for (int m = 0; m < 2; ++m)
#pragma unroll
    for (int n = 0; n < 2; ++n)
#pragma unroll
      for (int r = 0; r < 4; ++r) {
        int row = wr * 32 + m * 16 + fq * 4 + r, col = wc * 32 + n * 16 + fr;
        Obuf[(rowQ + row) * 512 + h * 64 + col] = oa[m][n][r] / rsum[row];
      }
}

// ---------------- swish + LayerNorm over D=512 (wave per row), out bf16 ----------------
__global__ __launch_bounds__(256) void swish_ln(
    const float* __restrict__ O, ushort* __restrict__ X,
    const float* __restrict__ gamma, const float* __restrict__ beta)
{
  int row = blockIdx.x * 4 + (threadIdx.x >> 6);
  int lane = threadIdx.x & 63;
  const float* x = O + (size_t)row * 512 + lane * 8;
  float4 va = *(const float4*)(x);
  float4 vb = *(const float4*)(x + 4);
  float y[8] = {va.x, va.y, va.z, va.w, vb.x, vb.y, vb.z, vb.w};
  float s = 0.f, sq = 0.f;
#pragma unroll
  for (int i = 0; i < 8; ++i) {
    y[i] = y[i] / (1.f + __expf(-y[i]));
    s += y[i]; sq += y[i] * y[i];
  }
#pragma unroll
  for (int o = 1; o < 64; o <<= 1) { s += __shfl_xor(s, o); sq += __shfl_xor(sq, o); }
  float mean = s * (1.f / 512.f);
  float var = (sq - s * mean) * (1.f / 511.f);   // unbiased (ddof=1)
  float inv = 1.f / (sqrtf(var) + 1e-6f);
  const float4 g0 = *(const float4*)(gamma + lane * 8);
  const float4 g1 = *(const float4*)(gamma + lane * 8 + 4);
  const float4 b0 = *(const float4*)(beta + lane * 8);
  const float4 b1 = *(const float4*)(beta + lane * 8 + 4);
  float gg[8] = {g0.x, g0.y, g0.z, g0.w, g1.x, g1.y, g1.z, g1.w};
  float bb[8] = {b0.x, b0.y, b0.z, b0.w, b1.x, b1.y, b1.z, b1.w};
  ushort u[8];
#pragma unroll
  for (int i = 0; i < 8; ++i) u[i] = f2bf(gg[i] * (y[i] - mean) * inv + bb[i]);
  *(uint4*)(X + (size_t)row * 512 + lane * 8) = *(uint4*)u;
}

// ---------------- fc GEMM + residual + BN partial sums ----------------
__global__ __launch_bounds__(256) void gemm_fc(
    const ushort* __restrict__ A, const ushort* __restrict__ Bm,
    const float* __restrict__ resid, float* __restrict__ out,
    float* __restrict__ bn_sum, float* __restrict__ bn_sq)
{
  __shared__ __align__(16) ushort At[128 * 64];
  __shared__ __align__(16) ushort Bt[128 * 64];
  __shared__ float csum[128], csq[128];
  const int K = 512;
  int rowBase = blockIdx.x * 128;   // 16
  int colBase = blockIdx.y * 128;   // 32
  int tid = threadIdx.x, l = tid & 63, w = tid >> 6;
  int wr = w >> 1, wc = w & 1, fr = l & 15, fq = l >> 4;
  if (tid < 128) { csum[tid] = 0.f; csq[tid] = 0.f; }
  f32x4 acc[4][4];
#pragma unroll
  for (int m = 0; m < 4; ++m)
#pragma unroll
    for (int n = 0; n < 4; ++n) acc[m][n] = (f32x4){0.f, 0.f, 0.f, 0.f};

  for (int kt = 0; kt < K; kt += 64) {
#pragma unroll
    for (int j = 0; j < 4; ++j) {
      int c = ((w * 4 + j) << 6) + l;
      int row = c >> 3, cc = c & 7;
      __builtin_amdgcn_global_load_lds(AS1(A + (size_t)(rowBase + row) * K + kt + cc * 8),
                                       AS3((char*)At + (w * 4 + j) * 1024), 16, 0, 0);
      __builtin_amdgcn_global_load_lds(AS1(Bm + (size_t)(colBase + row) * K + kt + cc * 8),
                                       AS3((char*)Bt + (w * 4 + j) * 1024), 16, 0, 0);
    }
    __syncthreads();
#pragma unroll
    for (int kc = 0; kc < 2; ++kc) {
      bf16x8 af[4], bfv[4];
#pragma unroll
      for (int m = 0; m < 4; ++m)
        af[m] = *(const bf16x8*)&At[(wr * 64 + m * 16 + fr) * 64 + kc * 32 + fq * 8];
#pragma unroll
      for (int n = 0; n < 4; ++n)
        bfv[n] = *(const bf16x8*)&Bt[(wc * 64 + n * 16 + fr) * 64 + kc * 32 + fq * 8];
#pragma unroll
      for (int m = 0; m < 4; ++m)
#pragma unroll
        for (int n = 0; n < 4; ++n)
          acc[m][n] = __builtin_amdgcn_mfma_f32_16x16x32_bf16(af[m], bfv[n], acc[m][n], 0, 0, 0);
    }
    __syncthreads();
  }
  // epilogue: out = acc + residual; per-channel partial sums for BN
#pragma unroll
  for (int m = 0; m < 4; ++m)
#pragma unroll
    for (int r = 0; r < 4; ++r) {
      float ps = 0.f, pq = 0.f;
#pragma unroll
      for (int n = 0; n < 4; ++n) {
        int row = rowBase + wr * 64 + m * 16 + fq * 4 + r;
        int col = colBase + wc * 64 + n * 16 + fr;
        size_t idx = (size_t)row * 4096 + col;
        float val = acc[m][n][r] + resid[idx];
        out[idx] = val;
        ps += val; pq += val * val;
      }
#pragma unroll
      for (int o = 1; o < 16; o <<= 1) { ps += __shfl_xor(ps, o); pq += __shfl_xor(pq, o); }
      if (fr == 0) {
        int ch = wr * 64 + m * 16 + fq * 4 + r;   // rowBase % 128 == 0
        atomicAdd(&csum[ch], ps);
        atomicAdd(&csq[ch], pq);
      }
    }
  __syncthreads();
  if (tid < 128) {
    atomicAdd(&bn_sum[tid], csum[tid]);
    atomicAdd(&bn_sq[tid], csq[tid]);
  }
}

// ---------------- BatchNorm finalize (in place on d_out) ----------------
__global__ __launch_bounds__(256) void bn_norm(
    float* __restrict__ out, const float* __restrict__ bn_sum, const float* __restrict__ bn_sq,
    const float* __restrict__ gamma, const float* __restrict__ beta)
{
  const float inv_n = 1.f / 65536.f;
  int stride = gridDim.x * blockDim.x;
  for (int v = blockIdx.x * blockDim.x + threadIdx.x; v < 2097152; v += stride) {
    int elem = v * 4;
    int ch = (elem >> 12) & 127;
    float mean = bn_sum[ch] * inv_n;
    float var = bn_sq[ch] * inv_n - mean * mean;
    float g = gamma[ch] * rsqrtf(var + 1e-5f);
    float bta = beta[ch];
    float4 x = *(float4*)(out + elem);
    x.x = (x.x - mean) * g + bta;
    x.y = (x.y - mean) * g + bta;
    x.z = (x.z - mean) * g + bta;
    x.w = (x.w - mean) * g + bta;
    *(float4*)(out + elem) = x;
  }
}

extern "C" void kernel_launch(void* const* d_in, const int* in_sizes, int n_in,
                              void* d_out, int out_size, void* d_ws, size_t ws_size,
                              hipStream_t stream)
{
  const float* v_in = (const float*)d_in[0];
  const float* k_in = (const float*)d_in[1];
  const float* q_in = (const float*)d_in[2];
  const float* w_qs = (const float*)d_in[3];
  const float* w_ks = (const float*)d_in[4];
  const float* w_vs = (const float*)d_in[5];
  const float* w_fc = (const float*)d_in[6];
  const float* ln_g = (const float*)d_in[7];
  const float* ln_b = (const float*)d_in[8];
  const float* temp = (const float*)d_in[9];
  const float* bn_g = (const float*)d_in[10];
  const float* bn_b = (const float*)d_in[11];
  float* out = (float*)d_out;

  char* ws = (char*)d_ws;
  size_t off = 0;
  auto alloc = [&](size_t bytes) { char* p = ws + off; off += bytes; return p; };
  ushort* wq  = (ushort*)alloc(512ull * 4096 * 2);
  ushort* wk  = (ushort*)alloc(512ull * 4096 * 2);
  ushort* wv  = (ushort*)alloc(512ull * 4096 * 2);
  ushort* wfc = (ushort*)alloc(512ull * 4096 * 2);
  ushort* Qp  = (ushort*)alloc(2048ull * 512 * 2);
  ushort* Kp  = (ushort*)alloc(2048ull * 512 * 2);
  ushort* Vp  = (ushort*)alloc(2048ull * 512 * 2);
  float*  Obuf= (float*)alloc(2048ull * 512 * 4);
  ushort* X16 = (ushort*)alloc(2048ull * 512 * 2);
  float*  bns = (float*)alloc(128 * 4);
  float*  bnq = (float*)alloc(128 * 4);

  // split-K partial planes: 3*(1<<lgs) planes of 2048*512 fp32
  int lgs = 2;                       // 4-way split-K -> 768 blocks (~3 blocks/CU)
  if (off + (3ull << lgs) * 1048576 * 4 > ws_size) lgs = 1;
  if (off + (3ull << lgs) * 1048576 * 4 > ws_size) lgs = 0;
  float* part = (float*)alloc((3ull << lgs) * 1048576 * 4);

  hipMemsetAsync(bns, 0, 256 * 4, stream);   // zero bns+bnq (adjacent)

  pack4<<<dim3(512, 4), 256, 0, stream>>>(w_qs, w_ks, w_vs, w_fc, wq, wk, wv, wfc,
                                          512 * 4096);
  gemm_qkv<<<dim3(16, 4, 3 << lgs), 256, 0, stream>>>(q_in, k_in, v_in, wq, wk, wv, part, lgs);
  reduce_qkv<<<dim3(1024, 3), 256, 0, stream>>>(part, Qp, Kp, Vp, lgs);
  attn<<<dim3(2, 128), 256, 0, stream>>>(Qp, Kp, Vp, Obuf, temp);
  swish_ln<<<512, 256, 0, stream>>>(Obuf, X16, ln_g, ln_b);
  gemm_fc<<<dim3(16, 32), 256, 0, stream>>>(X16, wfc, v_in, out, bns, bnq);
  bn_norm<<<2048, 256, 0, stream>>>(out, bns, bnq, bn_g, bn_b);
}